// Round 1
// baseline (737.158 us; speedup 1.0000x reference)
//
#include <hip/hip_runtime.h>

constexpr int FIN = 128;   // input features (also total hidden width)
constexpr int HH  = 64;    // half hidden (GCN branch width)

// ---------------------------------------------------------------- degree ----
__global__ void k_init_deg(float* __restrict__ deg, int N) {
    int i = blockIdx.x * blockDim.x + threadIdx.x;
    if (i < N) deg[i] = 1.0f;                    // self-loop contributes 1
}

__global__ void k_deg(const int* __restrict__ col, float* __restrict__ deg, int E) {
    int e = blockIdx.x * blockDim.x + threadIdx.x;
    if (e < E) atomicAdd(deg + col[e], 1.0f);
}

__global__ void k_rsqrt(float* __restrict__ deg, int N) {
    int i = blockIdx.x * blockDim.x + threadIdx.x;
    if (i < N) deg[i] = rsqrtf(deg[i]);          // deg >= 1 always (self-loops)
}

// ------------------------------------------------------------------ GEMM ----
// xw[N,128] = x[N,128] @ [W1 | Wf1]   (W1,Wf1 are [128,64] row-major)
// Block: 256 threads, tile 64 nodes x 128 cols, K-chunks of 16.
__global__ __launch_bounds__(256) void k_gemm(
    const float* __restrict__ x, const float* __restrict__ W1,
    const float* __restrict__ Wf1, float* __restrict__ xw, int N)
{
    __shared__ float xs[16][68];     // [k][node], +4 pad: 16B-aligned rows, 2-way max on write
    __shared__ float ws[16][128];    // [k][col]

    const int tid = threadIdx.x;
    const int tx  = tid & 31;        // col group: cols tx*4 .. tx*4+3
    const int ty  = tid >> 5;        // node group: nodes ty*8 .. ty*8+7
    const int nbase = blockIdx.x * 64;

    float acc[8][4];
#pragma unroll
    for (int i = 0; i < 8; ++i)
#pragma unroll
        for (int j = 0; j < 4; ++j) acc[i][j] = 0.0f;

    // x-tile load mapping: row r = tid>>2 (0..63), k-offset kk0 = (tid&3)*4
    const int xr_row = tid >> 2;
    const int xr_kk0 = (tid & 3) * 4;
    int nload = nbase + xr_row;
    const int nclamped = (nload < N) ? nload : (N - 1);

    // w-tile load mapping: k = tid>>4 (0..15), c = (tid*8)&127 (multiple of 8)
    const int wk = tid >> 4;
    const int wc = (tid * 8) & 127;

    for (int k0 = 0; k0 < FIN; k0 += 16) {
        // ---- stage x tile (transposed into xs[k][node]) ----
        float4 xv = *(const float4*)(x + (size_t)nclamped * FIN + k0 + xr_kk0);
        xs[xr_kk0 + 0][xr_row] = xv.x;
        xs[xr_kk0 + 1][xr_row] = xv.y;
        xs[xr_kk0 + 2][xr_row] = xv.z;
        xs[xr_kk0 + 3][xr_row] = xv.w;
        // ---- stage w tile ----
        {
            const float* src = (wc < HH) ? (W1  + (size_t)(k0 + wk) * HH + wc)
                                         : (Wf1 + (size_t)(k0 + wk) * HH + (wc - HH));
            float4 w0 = *(const float4*)(src);
            float4 w1 = *(const float4*)(src + 4);
            *(float4*)&ws[wk][wc]     = w0;
            *(float4*)&ws[wk][wc + 4] = w1;
        }
        __syncthreads();

#pragma unroll
        for (int kk = 0; kk < 16; ++kk) {
            float4 xa = *(const float4*)&xs[kk][ty * 8];
            float4 xb = *(const float4*)&xs[kk][ty * 8 + 4];
            float4 wv = *(const float4*)&ws[kk][tx * 4];
            float xr[8] = {xa.x, xa.y, xa.z, xa.w, xb.x, xb.y, xb.z, xb.w};
#pragma unroll
            for (int i = 0; i < 8; ++i) {
                acc[i][0] = fmaf(xr[i], wv.x, acc[i][0]);
                acc[i][1] = fmaf(xr[i], wv.y, acc[i][1]);
                acc[i][2] = fmaf(xr[i], wv.z, acc[i][2]);
                acc[i][3] = fmaf(xr[i], wv.w, acc[i][3]);
            }
        }
        __syncthreads();
    }

#pragma unroll
    for (int i = 0; i < 8; ++i) {
        int n = nbase + ty * 8 + i;
        if (n < N) {
            float4 v = make_float4(acc[i][0], acc[i][1], acc[i][2], acc[i][3]);
            *(float4*)(xw + (size_t)n * FIN + tx * 4) = v;
        }
    }
}

// --------------------------------------------------- layer-1 aggregation ----
// One wave per edge (incl. N self-loops at the tail). Lane l handles feature l.
__global__ __launch_bounds__(256) void k_agg1(
    const int* __restrict__ ei, const float* __restrict__ dinv,
    const float* __restrict__ xw, float* __restrict__ agg, int N, int E)
{
    int m    = (blockIdx.x * blockDim.x + threadIdx.x) >> 6;  // wave id = edge id
    int lane = threadIdx.x & 63;
    int M = E + N;
    if (m >= M) return;
    int r, c; float nrm;
    if (m < E) {
        r = ei[m]; c = ei[E + m];
        nrm = dinv[r] * dinv[c];
    } else {
        r = c = m - E;
        float d = dinv[r]; nrm = d * d;
    }
    float v = xw[(size_t)r * FIN + lane] * nrm;   // lanes 0..63 = GCN branch cols
    atomicAdd(agg + (size_t)c * HH + lane, v);
}

// ------------------------------------------------------------- per node -----
// h = relu([agg + b1 | xw[:,64:] + bf1]);  z = h·W2;  out_base = h·Wf2 + b2 + bf2
__global__ __launch_bounds__(256) void k_node(
    const float* __restrict__ agg, const float* __restrict__ xw,
    const float* __restrict__ b1, const float* __restrict__ bf1,
    const float* __restrict__ W2, const float* __restrict__ Wf2,
    const float* __restrict__ b2, const float* __restrict__ bf2,
    float* __restrict__ z, float* __restrict__ out, int N)
{
    int i    = (blockIdx.x * blockDim.x + threadIdx.x) >> 6;
    int lane = threadIdx.x & 63;
    if (i >= N) return;
    float h0 = fmaxf(agg[(size_t)i * HH + lane] + b1[lane], 0.0f);
    float h1 = fmaxf(xw[(size_t)i * FIN + HH + lane] + bf1[lane], 0.0f);
    float zp = h0 * W2[lane]  + h1 * W2[HH + lane];
    float fp = h0 * Wf2[lane] + h1 * Wf2[HH + lane];
#pragma unroll
    for (int o = 32; o > 0; o >>= 1) {
        zp += __shfl_down(zp, o, 64);
        fp += __shfl_down(fp, o, 64);
    }
    if (lane == 0) {
        z[i]   = zp;
        out[i] = fp + b2[0] + bf2[0];
    }
}

// --------------------------------------------------- layer-2 aggregation ----
__global__ void k_agg2(const int* __restrict__ ei, const float* __restrict__ dinv,
                       const float* __restrict__ z, float* __restrict__ out,
                       int N, int E)
{
    int m = blockIdx.x * blockDim.x + threadIdx.x;
    int M = E + N;
    if (m >= M) return;
    int r, c; float nrm;
    if (m < E) {
        r = ei[m]; c = ei[E + m];
        nrm = dinv[r] * dinv[c];
    } else {
        r = c = m - E;
        float d = dinv[r]; nrm = d * d;
    }
    atomicAdd(out + c, z[r] * nrm);
}

// ---------------------------------------------------------------- launch ----
extern "C" void kernel_launch(void* const* d_in, const int* in_sizes, int n_in,
                              void* d_out, int out_size, void* d_ws, size_t ws_size,
                              hipStream_t stream)
{
    const float* x   = (const float*)d_in[0];
    const int*   ei  = (const int*)d_in[1];    // [2,E] row-major: row=ei[e], col=ei[E+e]
    const float* W1  = (const float*)d_in[2];
    const float* b1  = (const float*)d_in[3];
    const float* Wf1 = (const float*)d_in[4];
    const float* bf1 = (const float*)d_in[5];
    const float* W2  = (const float*)d_in[6];
    const float* b2  = (const float*)d_in[7];
    const float* Wf2 = (const float*)d_in[8];
    const float* bf2 = (const float*)d_in[9];

    const int N = in_sizes[0] / FIN;   // 100000
    const int E = in_sizes[1] / 2;     // 1600000
    float* out = (float*)d_out;

    // workspace layout (floats): xw[N*128] | agg[N*64] | dinv[N] | z[N]
    float* ws   = (float*)d_ws;
    float* xw   = ws;
    float* agg  = xw  + (size_t)N * FIN;
    float* dinv = agg + (size_t)N * HH;
    float* z    = dinv + N;

    hipMemsetAsync(agg, 0, (size_t)N * HH * sizeof(float), stream);

    k_init_deg<<<(N + 255) / 256, 256, 0, stream>>>(dinv, N);
    k_deg<<<(E + 255) / 256, 256, 0, stream>>>(ei + E, dinv, E);
    k_rsqrt<<<(N + 255) / 256, 256, 0, stream>>>(dinv, N);

    k_gemm<<<(N + 63) / 64, 256, 0, stream>>>(x, W1, Wf1, xw, N);

    {
        long M = (long)E + N;                  // one wave per edge/self-loop
        long threads = M * 64;
        int blocks = (int)((threads + 255) / 256);
        k_agg1<<<blocks, 256, 0, stream>>>(ei, dinv, xw, agg, N, E);
    }

    {
        long threads = (long)N * 64;           // one wave per node
        int blocks = (int)((threads + 255) / 256);
        k_node<<<blocks, 256, 0, stream>>>(agg, xw, b1, bf1, W2, Wf2, b2, bf2, z, out, N);
    }

    {
        long M = (long)E + N;
        int blocks = (int)((M + 255) / 256);
        k_agg2<<<blocks, 256, 0, stream>>>(ei, dinv, z, out, N, E);
    }
}

// Round 2
// 440.254 us; speedup vs baseline: 1.6744x; 1.6744x over previous
//
#include <hip/hip_runtime.h>

constexpr int FIN = 128;   // input features (also total hidden width)
constexpr int HH  = 64;    // half hidden (GCN branch width)

// ------------------------------------------------------------------ GEMM ----
// xw[N,128] = x[N,128] @ [W1 | Wf1]   (W1,Wf1 are [128,64] row-major)
__global__ __launch_bounds__(256) void k_gemm(
    const float* __restrict__ x, const float* __restrict__ W1,
    const float* __restrict__ Wf1, float* __restrict__ xw, int N)
{
    __shared__ float xs[16][68];     // [k][node], +4 pad
    __shared__ float ws[16][128];    // [k][col]

    const int tid = threadIdx.x;
    const int tx  = tid & 31;        // col group: cols tx*4 .. tx*4+3
    const int ty  = tid >> 5;        // node group: nodes ty*8 .. ty*8+7
    const int nbase = blockIdx.x * 64;

    float acc[8][4];
#pragma unroll
    for (int i = 0; i < 8; ++i)
#pragma unroll
        for (int j = 0; j < 4; ++j) acc[i][j] = 0.0f;

    const int xr_row = tid >> 2;
    const int xr_kk0 = (tid & 3) * 4;
    int nload = nbase + xr_row;
    const int nclamped = (nload < N) ? nload : (N - 1);

    const int wk = tid >> 4;
    const int wc = (tid * 8) & 127;

    for (int k0 = 0; k0 < FIN; k0 += 16) {
        float4 xv = *(const float4*)(x + (size_t)nclamped * FIN + k0 + xr_kk0);
        xs[xr_kk0 + 0][xr_row] = xv.x;
        xs[xr_kk0 + 1][xr_row] = xv.y;
        xs[xr_kk0 + 2][xr_row] = xv.z;
        xs[xr_kk0 + 3][xr_row] = xv.w;
        {
            const float* src = (wc < HH) ? (W1  + (size_t)(k0 + wk) * HH + wc)
                                         : (Wf1 + (size_t)(k0 + wk) * HH + (wc - HH));
            float4 w0 = *(const float4*)(src);
            float4 w1 = *(const float4*)(src + 4);
            *(float4*)&ws[wk][wc]     = w0;
            *(float4*)&ws[wk][wc + 4] = w1;
        }
        __syncthreads();

#pragma unroll
        for (int kk = 0; kk < 16; ++kk) {
            float4 xa = *(const float4*)&xs[kk][ty * 8];
            float4 xb = *(const float4*)&xs[kk][ty * 8 + 4];
            float4 wv = *(const float4*)&ws[kk][tx * 4];
            float xr[8] = {xa.x, xa.y, xa.z, xa.w, xb.x, xb.y, xb.z, xb.w};
#pragma unroll
            for (int i = 0; i < 8; ++i) {
                acc[i][0] = fmaf(xr[i], wv.x, acc[i][0]);
                acc[i][1] = fmaf(xr[i], wv.y, acc[i][1]);
                acc[i][2] = fmaf(xr[i], wv.z, acc[i][2]);
                acc[i][3] = fmaf(xr[i], wv.w, acc[i][3]);
            }
        }
        __syncthreads();
    }

#pragma unroll
    for (int i = 0; i < 8; ++i) {
        int n = nbase + ty * 8 + i;
        if (n < N) {
            float4 v = make_float4(acc[i][0], acc[i][1], acc[i][2], acc[i][3]);
            *(float4*)(xw + (size_t)n * FIN + tx * 4) = v;
        }
    }
}

// ------------------------------------------------------------ CSR build -----
__global__ void k_count(const int* __restrict__ col, int* __restrict__ cnt, int E) {
    int e = blockIdx.x * blockDim.x + threadIdx.x;
    if (e < E) atomicAdd(cnt + col[e], 1);
}

// block-local exclusive scan over chunks of 1024, emit block totals
__global__ __launch_bounds__(256) void k_scan1(
    const int* __restrict__ cnt, int* __restrict__ off, int* __restrict__ bsum, int N)
{
    __shared__ int s[256];
    const int t = threadIdx.x;
    const int idx = blockIdx.x * 1024 + t * 4;
    int v[4]; int mysum = 0;
#pragma unroll
    for (int j = 0; j < 4; ++j) {
        v[j] = (idx + j < N) ? cnt[idx + j] : 0;
        mysum += v[j];
    }
    s[t] = mysum;
    __syncthreads();
    for (int o = 1; o < 256; o <<= 1) {
        int y = (t >= o) ? s[t - o] : 0;
        __syncthreads();
        s[t] += y;
        __syncthreads();
    }
    int running = s[t] - mysum;   // block-local exclusive prefix
#pragma unroll
    for (int j = 0; j < 4; ++j) {
        if (idx + j < N) off[idx + j] = running;
        running += v[j];
    }
    if (t == 255) bsum[blockIdx.x] = s[255];
}

__global__ void k_scan2(int* __restrict__ bsum, int nb) {
    if (threadIdx.x == 0 && blockIdx.x == 0) {
        int run = 0;
        for (int i = 0; i < nb; ++i) { int v = bsum[i]; bsum[i] = run; run += v; }
    }
}

// add block offsets; snapshot cur=off; dinv = rsqrt(cnt+1)  (self-loop incl.)
__global__ void k_scan3(const int* __restrict__ cnt, int* __restrict__ off,
                        int* __restrict__ cur, const int* __restrict__ bsum,
                        float* __restrict__ dinv, int N)
{
    int i = blockIdx.x * blockDim.x + threadIdx.x;
    if (i < N) {
        int o = off[i] + bsum[i >> 10];
        off[i] = o;
        cur[i] = o;
        dinv[i] = rsqrtf((float)cnt[i] + 1.0f);
    }
}

// sedge[pos] = {row, norm}  grouped by target col
__global__ void k_scatter(const int* __restrict__ ei, int* __restrict__ cur,
                          const float* __restrict__ dinv, int2* __restrict__ sedge, int E)
{
    int e = blockIdx.x * blockDim.x + threadIdx.x;
    if (e >= E) return;
    int r = ei[e], c = ei[E + e];
    float nrm = dinv[r] * dinv[c];
    int pos = atomicAdd(cur + c, 1);
    sedge[pos] = make_int2(r, __float_as_int(nrm));
}

// ------------------------- fused: layer-1 aggregate + relu + layer-2 dots ---
// one wave per node; lane = feature (0..63)
__global__ __launch_bounds__(256) void k_fused(
    const int* __restrict__ off, const int* __restrict__ cur,
    const int2* __restrict__ sedge, const float* __restrict__ dinv,
    const float* __restrict__ xw,
    const float* __restrict__ b1, const float* __restrict__ bf1,
    const float* __restrict__ W2, const float* __restrict__ Wf2,
    const float* __restrict__ b2, const float* __restrict__ bf2,
    float* __restrict__ z, float* __restrict__ out, int N)
{
    int i    = (blockIdx.x * blockDim.x + threadIdx.x) >> 6;
    int lane = threadIdx.x & 63;
    if (i >= N) return;

    int jb = off[i], je = cur[i];      // cur[i] == off[i]+cnt[i] after scatter
    float acc = 0.0f;
    int2 ep = (jb < je) ? sedge[jb] : make_int2(0, 0);
    for (int j = jb; j < je; ++j) {
        int2 nxt = (j + 1 < je) ? sedge[j + 1] : make_int2(0, 0);   // prefetch
        acc = fmaf(xw[(size_t)ep.x * FIN + lane], __int_as_float(ep.y), acc);
        ep = nxt;
    }
    float di = dinv[i];
    acc = fmaf(xw[(size_t)i * FIN + lane], di * di, acc);   // self loop

    float h0 = fmaxf(acc + b1[lane], 0.0f);
    float h1 = fmaxf(xw[(size_t)i * FIN + HH + lane] + bf1[lane], 0.0f);
    float zp = h0 * W2[lane]  + h1 * W2[HH + lane];
    float fp = h0 * Wf2[lane] + h1 * Wf2[HH + lane];
#pragma unroll
    for (int o = 32; o > 0; o >>= 1) {
        zp += __shfl_down(zp, o, 64);
        fp += __shfl_down(fp, o, 64);
    }
    if (lane == 0) {
        z[i]   = zp;
        out[i] = fp + b2[0] + bf2[0];
    }
}

// ------------------------------------------- layer-2 aggregate (CSR) --------
// one thread per node
__global__ void k_agg2(const int* __restrict__ off, const int* __restrict__ cur,
                       const int2* __restrict__ sedge, const float* __restrict__ dinv,
                       const float* __restrict__ z, float* __restrict__ out, int N)
{
    int i = blockIdx.x * blockDim.x + threadIdx.x;
    if (i >= N) return;
    float s = 0.0f;
    int je = cur[i];
    for (int j = off[i]; j < je; ++j) {
        int2 ep = sedge[j];
        s = fmaf(z[ep.x], __int_as_float(ep.y), s);
    }
    float di = dinv[i];
    out[i] += fmaf(z[i], di * di, s);
}

// ---------------------------------------------------------------- launch ----
extern "C" void kernel_launch(void* const* d_in, const int* in_sizes, int n_in,
                              void* d_out, int out_size, void* d_ws, size_t ws_size,
                              hipStream_t stream)
{
    const float* x   = (const float*)d_in[0];
    const int*   ei  = (const int*)d_in[1];    // [2,E]: row=ei[e], col=ei[E+e]
    const float* W1  = (const float*)d_in[2];
    const float* b1  = (const float*)d_in[3];
    const float* Wf1 = (const float*)d_in[4];
    const float* bf1 = (const float*)d_in[5];
    const float* W2  = (const float*)d_in[6];
    const float* b2  = (const float*)d_in[7];
    const float* Wf2 = (const float*)d_in[8];
    const float* bf2 = (const float*)d_in[9];

    const int N = in_sizes[0] / FIN;   // 100000
    const int E = in_sizes[1] / 2;     // 1600000
    float* out = (float*)d_out;

    // workspace layout (4-byte units), all offsets 8B-aligned:
    // xw[N*128] | dinv[N] | z[N] | cnt[N] | off[N] | cur[N] | bsum[pad] | sedge[2*E]
    const int nb = (N + 1023) / 1024;
    float* ws   = (float*)d_ws;
    float* xw   = ws;
    float* dinv = xw + (size_t)N * FIN;
    float* z    = dinv + N;
    int*   cnt  = (int*)(z + N);
    int*   off  = cnt + N;
    int*   cur  = off + N;
    int*   bsum = cur + N;
    int    bpad = (nb + 2) & ~1;               // keep 8B alignment
    int2*  sedge = (int2*)(bsum + bpad);

    hipMemsetAsync(cnt, 0, (size_t)N * sizeof(int), stream);

    k_count<<<(E + 255) / 256, 256, 0, stream>>>(ei + E, cnt, E);
    k_scan1<<<nb, 256, 0, stream>>>(cnt, off, bsum, N);
    k_scan2<<<1, 64, 0, stream>>>(bsum, nb);
    k_scan3<<<(N + 255) / 256, 256, 0, stream>>>(cnt, off, cur, bsum, dinv, N);
    k_scatter<<<(E + 255) / 256, 256, 0, stream>>>(ei, cur, dinv, sedge, E);

    k_gemm<<<(N + 63) / 64, 256, 0, stream>>>(x, W1, Wf1, xw, N);

    {
        long threads = (long)N * 64;           // one wave per node
        int blocks = (int)((threads + 255) / 256);
        k_fused<<<blocks, 256, 0, stream>>>(off, cur, sedge, dinv, xw,
                                            b1, bf1, W2, Wf2, b2, bf2, z, out, N);
    }

    k_agg2<<<(N + 255) / 256, 256, 0, stream>>>(off, cur, sedge, dinv, z, out, N);
}

// Round 3
// 373.345 us; speedup vs baseline: 1.9745x; 1.1792x over previous
//
#include <hip/hip_runtime.h>

constexpr int FIN = 128;   // input features (also total hidden width)
constexpr int HH  = 64;    // half hidden (GCN branch width)

// ------------------------------------------------------------------ GEMM ----
// xw[N,128] = x[N,128] @ [W1 | Wf1]   (W1,Wf1 are [128,64] row-major)
__global__ __launch_bounds__(256) void k_gemm(
    const float* __restrict__ x, const float* __restrict__ W1,
    const float* __restrict__ Wf1, float* __restrict__ xw, int N)
{
    __shared__ float xs[16][68];     // [k][node], +4 pad
    __shared__ float ws[16][128];    // [k][col]

    const int tid = threadIdx.x;
    const int tx  = tid & 31;        // col group: cols tx*4 .. tx*4+3
    const int ty  = tid >> 5;        // node group: nodes ty*8 .. ty*8+7
    const int nbase = blockIdx.x * 64;

    float acc[8][4];
#pragma unroll
    for (int i = 0; i < 8; ++i)
#pragma unroll
        for (int j = 0; j < 4; ++j) acc[i][j] = 0.0f;

    const int xr_row = tid >> 2;
    const int xr_kk0 = (tid & 3) * 4;
    int nload = nbase + xr_row;
    const int nclamped = (nload < N) ? nload : (N - 1);

    const int wk = tid >> 4;
    const int wc = (tid * 8) & 127;

    for (int k0 = 0; k0 < FIN; k0 += 16) {
        float4 xv = *(const float4*)(x + (size_t)nclamped * FIN + k0 + xr_kk0);
        xs[xr_kk0 + 0][xr_row] = xv.x;
        xs[xr_kk0 + 1][xr_row] = xv.y;
        xs[xr_kk0 + 2][xr_row] = xv.z;
        xs[xr_kk0 + 3][xr_row] = xv.w;
        {
            const float* src = (wc < HH) ? (W1  + (size_t)(k0 + wk) * HH + wc)
                                         : (Wf1 + (size_t)(k0 + wk) * HH + (wc - HH));
            float4 w0 = *(const float4*)(src);
            float4 w1 = *(const float4*)(src + 4);
            *(float4*)&ws[wk][wc]     = w0;
            *(float4*)&ws[wk][wc + 4] = w1;
        }
        __syncthreads();

#pragma unroll
        for (int kk = 0; kk < 16; ++kk) {
            float4 xa = *(const float4*)&xs[kk][ty * 8];
            float4 xb = *(const float4*)&xs[kk][ty * 8 + 4];
            float4 wv = *(const float4*)&ws[kk][tx * 4];
            float xr[8] = {xa.x, xa.y, xa.z, xa.w, xb.x, xb.y, xb.z, xb.w};
#pragma unroll
            for (int i = 0; i < 8; ++i) {
                acc[i][0] = fmaf(xr[i], wv.x, acc[i][0]);
                acc[i][1] = fmaf(xr[i], wv.y, acc[i][1]);
                acc[i][2] = fmaf(xr[i], wv.z, acc[i][2]);
                acc[i][3] = fmaf(xr[i], wv.w, acc[i][3]);
            }
        }
        __syncthreads();
    }

#pragma unroll
    for (int i = 0; i < 8; ++i) {
        int n = nbase + ty * 8 + i;
        if (n < N) {
            float4 v = make_float4(acc[i][0], acc[i][1], acc[i][2], acc[i][3]);
            *(float4*)(xw + (size_t)n * FIN + tx * 4) = v;
        }
    }
}

// ------------------------------------------------------------ CSR build -----
__global__ void k_count(const int* __restrict__ col, int* __restrict__ cnt, int E) {
    int e = blockIdx.x * blockDim.x + threadIdx.x;
    if (e < E) atomicAdd(cnt + col[e], 1);
}

// block-local exclusive scan over chunks of 1024, emit block totals
__global__ __launch_bounds__(256) void k_scan1(
    const int* __restrict__ cnt, int* __restrict__ off, int* __restrict__ bsum, int N)
{
    __shared__ int s[256];
    const int t = threadIdx.x;
    const int idx = blockIdx.x * 1024 + t * 4;
    int v[4]; int mysum = 0;
#pragma unroll
    for (int j = 0; j < 4; ++j) {
        v[j] = (idx + j < N) ? cnt[idx + j] : 0;
        mysum += v[j];
    }
    s[t] = mysum;
    __syncthreads();
    for (int o = 1; o < 256; o <<= 1) {
        int y = (t >= o) ? s[t - o] : 0;
        __syncthreads();
        s[t] += y;
        __syncthreads();
    }
    int running = s[t] - mysum;   // block-local exclusive prefix
#pragma unroll
    for (int j = 0; j < 4; ++j) {
        if (idx + j < N) off[idx + j] = running;
        running += v[j];
    }
    if (t == 255) bsum[blockIdx.x] = s[255];
}

__global__ void k_scan2(int* __restrict__ bsum, int nb) {
    if (threadIdx.x == 0 && blockIdx.x == 0) {
        int run = 0;
        for (int i = 0; i < nb; ++i) { int v = bsum[i]; bsum[i] = run; run += v; }
    }
}

// add block offsets; snapshot cur=off; dinv = rsqrt(cnt+1)  (self-loop incl.)
__global__ void k_scan3(const int* __restrict__ cnt, int* __restrict__ off,
                        int* __restrict__ cur, const int* __restrict__ bsum,
                        float* __restrict__ dinv, int N)
{
    int i = blockIdx.x * blockDim.x + threadIdx.x;
    if (i < N) {
        int o = off[i] + bsum[i >> 10];
        off[i] = o;
        cur[i] = o;
        dinv[i] = rsqrtf((float)cnt[i] + 1.0f);
    }
}

// sedge[pos] = {row, norm}  grouped by target col
__global__ void k_scatter(const int* __restrict__ ei, int* __restrict__ cur,
                          const float* __restrict__ dinv, int2* __restrict__ sedge, int E)
{
    int e = blockIdx.x * blockDim.x + threadIdx.x;
    if (e >= E) return;
    int r = ei[e], c = ei[E + e];
    float nrm = dinv[r] * dinv[c];
    int pos = atomicAdd(cur + c, 1);
    sedge[pos] = make_int2(r, __float_as_int(nrm));
}

// ------------------------- fused: layer-1 aggregate + relu + layer-2 dots ---
// one wave per node; 4 groups of 16 lanes process 4 edges concurrently,
// each lane loads float4 (16 lanes cover the 64 GCN features).
__global__ __launch_bounds__(256) void k_fused(
    const int* __restrict__ off, const int* __restrict__ cur,
    const int2* __restrict__ sedge, const float* __restrict__ dinv,
    const float* __restrict__ xw,
    const float* __restrict__ b1, const float* __restrict__ bf1,
    const float* __restrict__ W2, const float* __restrict__ Wf2,
    const float* __restrict__ b2, const float* __restrict__ bf2,
    float* __restrict__ z, float* __restrict__ out, int N)
{
    const int wid  = (blockIdx.x * blockDim.x + threadIdx.x) >> 6;  // node id
    const int lane = threadIdx.x & 63;
    const int g    = lane >> 4;        // edge group 0..3
    const int l16  = lane & 15;        // feature quad: features l16*4..+3
    const int i    = (wid < N) ? wid : (N - 1);

    const int jb  = off[i];
    const int deg = cur[i] - jb;

    // one coalesced load grabs the whole edge list (deg <= 64 virtually always)
    int2 er = make_int2(i, 0);
    if (lane < deg) er = sedge[jb + lane];

    float4 acc = make_float4(0.f, 0.f, 0.f, 0.f);
    const int lim = (deg < 64) ? deg : 64;
    for (int t0 = 0; t0 < lim; t0 += 4) {
        int  tt    = t0 + g;
        bool valid = tt < lim;
        int  row   = __shfl(er.x, tt, 64);
        int  nrmi  = __shfl(er.y, tt, 64);
        row        = valid ? row : i;
        float s    = valid ? __int_as_float(nrmi) : 0.0f;
        float4 v = *(const float4*)(xw + (size_t)row * FIN + l16 * 4);
        acc.x = fmaf(v.x, s, acc.x);
        acc.y = fmaf(v.y, s, acc.y);
        acc.z = fmaf(v.z, s, acc.z);
        acc.w = fmaf(v.w, s, acc.w);
    }
    // rare tail: deg > 64
    for (int j = jb + 64 + g; j < jb + deg; j += 4) {
        int2 ep = sedge[j];
        float s = __int_as_float(ep.y);
        float4 v = *(const float4*)(xw + (size_t)ep.x * FIN + l16 * 4);
        acc.x = fmaf(v.x, s, acc.x);
        acc.y = fmaf(v.y, s, acc.y);
        acc.z = fmaf(v.z, s, acc.z);
        acc.w = fmaf(v.w, s, acc.w);
    }

    // combine the 4 edge-groups
    acc.x += __shfl_xor(acc.x, 16, 64); acc.x += __shfl_xor(acc.x, 32, 64);
    acc.y += __shfl_xor(acc.y, 16, 64); acc.y += __shfl_xor(acc.y, 32, 64);
    acc.z += __shfl_xor(acc.z, 16, 64); acc.z += __shfl_xor(acc.z, 32, 64);
    acc.w += __shfl_xor(acc.w, 16, 64); acc.w += __shfl_xor(acc.w, 32, 64);

    // self loop
    float di = dinv[i];
    float dd = di * di;
    float4 sv = *(const float4*)(xw + (size_t)i * FIN + l16 * 4);
    acc.x = fmaf(sv.x, dd, acc.x);
    acc.y = fmaf(sv.y, dd, acc.y);
    acc.z = fmaf(sv.z, dd, acc.z);
    acc.w = fmaf(sv.w, dd, acc.w);

    // epilogue: relu + two 128-dots (each lane covers features l16*4..+3 of
    // both halves; groups are redundant replicas)
    float4 b1v  = *(const float4*)(b1  + l16 * 4);
    float4 bf1v = *(const float4*)(bf1 + l16 * 4);
    float4 x1   = *(const float4*)(xw + (size_t)i * FIN + HH + l16 * 4);
    float4 h0, h1;
    h0.x = fmaxf(acc.x + b1v.x, 0.f);  h0.y = fmaxf(acc.y + b1v.y, 0.f);
    h0.z = fmaxf(acc.z + b1v.z, 0.f);  h0.w = fmaxf(acc.w + b1v.w, 0.f);
    h1.x = fmaxf(x1.x + bf1v.x, 0.f);  h1.y = fmaxf(x1.y + bf1v.y, 0.f);
    h1.z = fmaxf(x1.z + bf1v.z, 0.f);  h1.w = fmaxf(x1.w + bf1v.w, 0.f);

    float4 w2a  = *(const float4*)(W2  + l16 * 4);
    float4 w2b  = *(const float4*)(W2  + HH + l16 * 4);
    float4 wf2a = *(const float4*)(Wf2 + l16 * 4);
    float4 wf2b = *(const float4*)(Wf2 + HH + l16 * 4);

    float zp = h0.x * w2a.x + h0.y * w2a.y + h0.z * w2a.z + h0.w * w2a.w
             + h1.x * w2b.x + h1.y * w2b.y + h1.z * w2b.z + h1.w * w2b.w;
    float fp = h0.x * wf2a.x + h0.y * wf2a.y + h0.z * wf2a.z + h0.w * wf2a.w
             + h1.x * wf2b.x + h1.y * wf2b.y + h1.z * wf2b.z + h1.w * wf2b.w;
#pragma unroll
    for (int o = 8; o > 0; o >>= 1) {
        zp += __shfl_xor(zp, o, 64);
        fp += __shfl_xor(fp, o, 64);
    }
    if (lane == 0 && wid < N) {
        z[i]   = zp;
        out[i] = fp + b2[0] + bf2[0];
    }
}

// ------------------------------------------- layer-2 aggregate (CSR) --------
// one wave per 4 nodes: 16 lanes stride a node's edge list in parallel
__global__ __launch_bounds__(256) void k_agg2(
    const int* __restrict__ off, const int* __restrict__ cur,
    const int2* __restrict__ sedge, const float* __restrict__ dinv,
    const float* __restrict__ z, float* __restrict__ out, int N)
{
    const int wid  = (blockIdx.x * blockDim.x + threadIdx.x) >> 6;
    const int lane = threadIdx.x & 63;
    const int g    = lane >> 4;
    const int l16  = lane & 15;
    int i = wid * 4 + g;
    bool ok = (i < N);
    i = ok ? i : (N - 1);

    const int jb = off[i], je = cur[i];
    float s = 0.0f;
    for (int j = jb + l16; j < je; j += 16) {
        int2 ep = sedge[j];
        s = fmaf(z[ep.x], __int_as_float(ep.y), s);
    }
#pragma unroll
    for (int o = 8; o > 0; o >>= 1) s += __shfl_xor(s, o, 64);
    if (l16 == 0 && ok) {
        float di = dinv[i];
        out[i] += fmaf(z[i], di * di, s);
    }
}

// ---------------------------------------------------------------- launch ----
extern "C" void kernel_launch(void* const* d_in, const int* in_sizes, int n_in,
                              void* d_out, int out_size, void* d_ws, size_t ws_size,
                              hipStream_t stream)
{
    const float* x   = (const float*)d_in[0];
    const int*   ei  = (const int*)d_in[1];    // [2,E]: row=ei[e], col=ei[E+e]
    const float* W1  = (const float*)d_in[2];
    const float* b1  = (const float*)d_in[3];
    const float* Wf1 = (const float*)d_in[4];
    const float* bf1 = (const float*)d_in[5];
    const float* W2  = (const float*)d_in[6];
    const float* b2  = (const float*)d_in[7];
    const float* Wf2 = (const float*)d_in[8];
    const float* bf2 = (const float*)d_in[9];

    const int N = in_sizes[0] / FIN;   // 100000
    const int E = in_sizes[1] / 2;     // 1600000
    float* out = (float*)d_out;

    // workspace layout (4-byte units), all offsets 8B-aligned:
    // xw[N*128] | dinv[N] | z[N] | cnt[N] | off[N] | cur[N] | bsum[pad] | sedge[2*E]
    const int nb = (N + 1023) / 1024;
    float* ws   = (float*)d_ws;
    float* xw   = ws;
    float* dinv = xw + (size_t)N * FIN;
    float* z    = dinv + N;
    int*   cnt  = (int*)(z + N);
    int*   off  = cnt + N;
    int*   cur  = off + N;
    int*   bsum = cur + N;
    int    bpad = (nb + 2) & ~1;               // keep 8B alignment
    int2*  sedge = (int2*)(bsum + bpad);

    hipMemsetAsync(cnt, 0, (size_t)N * sizeof(int), stream);

    k_count<<<(E + 255) / 256, 256, 0, stream>>>(ei + E, cnt, E);
    k_scan1<<<nb, 256, 0, stream>>>(cnt, off, bsum, N);
    k_scan2<<<1, 64, 0, stream>>>(bsum, nb);
    k_scan3<<<(N + 255) / 256, 256, 0, stream>>>(cnt, off, cur, bsum, dinv, N);
    k_scatter<<<(E + 255) / 256, 256, 0, stream>>>(ei, cur, dinv, sedge, E);

    k_gemm<<<(N + 63) / 64, 256, 0, stream>>>(x, W1, Wf1, xw, N);

    {
        long threads = (long)N * 64;           // one wave per node
        int blocks = (int)((threads + 255) / 256);
        k_fused<<<blocks, 256, 0, stream>>>(off, cur, sedge, dinv, xw,
                                            b1, bf1, W2, Wf2, b2, bf2, z, out, N);
    }

    {
        long waves = ((long)N + 3) / 4;        // one wave per 4 nodes
        int blocks = (int)((waves * 64 + 255) / 256);
        k_agg2<<<blocks, 256, 0, stream>>>(off, cur, sedge, dinv, z, out, N);
    }
}